// Round 1
// baseline (5114.629 us; speedup 1.0000x reference)
//
#include <hip/hip_runtime.h>
#include <cstddef>

#define DEVINF __builtin_inff()

// ---------------------------------------------------------------------------
// FPS: farthest point sampling, exact numpy semantics.
// One block (256 threads = 4 waves) per batch. Coords in regs, LDS copy for
// random access to the "last" point. argmax: strict-greater keeps the lowest
// index (numpy first-max), cross-lane/cross-wave compare uses (val, idx).
// ---------------------------------------------------------------------------
template <int N, int PPL>
__global__ __launch_bounds__(256) void fps_kernel(const float* __restrict__ pos,
                                                  int S, float* __restrict__ ctr) {
#pragma clang fp contract(off)
  const int b = blockIdx.x;
  const int tid = threadIdx.x;
  __shared__ float px[N], py[N], pz[N];
  __shared__ float rv[2][4];
  __shared__ int ri[2][4];
  for (int i = tid; i < N; i += 256) {
    px[i] = pos[((size_t)b * N + i) * 3 + 0];
    py[i] = pos[((size_t)b * N + i) * 3 + 1];
    pz[i] = pos[((size_t)b * N + i) * 3 + 2];
  }
  __syncthreads();
  float qx[PPL], qy[PPL], qz[PPL], d[PPL];
#pragma unroll
  for (int q = 0; q < PPL; ++q) {
    int i = q * 256 + tid;
    qx[q] = px[i]; qy[q] = py[i]; qz[q] = pz[i];
    d[q] = DEVINF;
  }
  int last = 0;
  for (int s = 0; s < S; ++s) {
    if (tid == 0) {
      ctr[((size_t)b * S + s) * 3 + 0] = px[last];
      ctr[((size_t)b * S + s) * 3 + 1] = py[last];
      ctr[((size_t)b * S + s) * 3 + 2] = pz[last];
    }
    float lx = px[last], ly = py[last], lz = pz[last];
    float bv = -DEVINF;
    int bi = 0x7fffffff;
#pragma unroll
    for (int q = 0; q < PPL; ++q) {
      float dx = qx[q] - lx, dy = qy[q] - ly, dz = qz[q] - lz;
      float t0 = dx * dx, t1 = dy * dy, t2 = dz * dz;
      float d2 = (t0 + t1) + t2;
      float dn = fminf(d[q], d2);
      d[q] = dn;
      int i = q * 256 + tid;
      if (dn > bv) { bv = dn; bi = i; }
    }
#pragma unroll
    for (int off = 1; off < 64; off <<= 1) {
      float ov = __shfl_xor(bv, off, 64);
      int oi = __shfl_xor(bi, off, 64);
      if (ov > bv || (ov == bv && oi < bi)) { bv = ov; bi = oi; }
    }
    int pb = s & 1;
    if ((tid & 63) == 0) { rv[pb][tid >> 6] = bv; ri[pb][tid >> 6] = bi; }
    __syncthreads();
    float fv = rv[pb][0];
    int fi = ri[pb][0];
#pragma unroll
    for (int w = 1; w < 4; ++w) {
      float ov = rv[pb][w];
      int oi = ri[pb][w];
      if (ov > fv || (ov == fv && oi < fi)) { fv = ov; fi = oi; }
    }
    last = fi;
  }
}

// ---------------------------------------------------------------------------
// SA1: ball query (first 64 in-radius by index) + MLP 12->64->64->128 + maxpool
// One wave per center. lane = edge. Weights via uniform (scalar) loads.
// h1/h2 bounce through LDS columns so k-loops can stay rolled.
// ---------------------------------------------------------------------------
__global__ __launch_bounds__(64, 2) void sa1_kernel(
    const float* __restrict__ x,    // [16][2048][9]
    const float* __restrict__ pos,  // [16][2048][3]
    const float* __restrict__ ctr,  // [16][1024][3]
    const float* __restrict__ w1, const float* __restrict__ b1,
    const float* __restrict__ w2, const float* __restrict__ b2,
    const float* __restrict__ w3, const float* __restrict__ b3,
    float* __restrict__ out)        // [16][1024][128]
{
  const int N = 2048;
  const float r2 = (float)(0.2 * 0.2);
  const int bs = blockIdx.x;
  const int b = bs >> 10;
  const int lane = threadIdx.x;
  const float cx = ctr[bs * 3 + 0], cy = ctr[bs * 3 + 1], cz = ctr[bs * 3 + 2];
  __shared__ int nb[64];
  __shared__ float hbuf[64][64];
  nb[lane] = 0;
  __syncthreads();
  int cnt = 0;
  {
#pragma clang fp contract(off)
    for (int base = 0; base < N && cnt < 64; base += 64) {
      int i = base + lane;
      const float* p = pos + ((size_t)b * N + i) * 3;
      float dx = p[0] - cx, dy = p[1] - cy, dz = p[2] - cz;
      float t0 = dx * dx, t1 = dy * dy, t2 = dz * dz;
      float d2 = (t0 + t1) + t2;
      bool inr = d2 <= r2;
      unsigned long long m = __ballot(inr);
      int posn = cnt + (int)__popcll(m & ((1ull << lane) - 1ull));
      if (inr && posn < 64) nb[posn] = i;
      cnt += (int)__popcll(m);
    }
  }
  __syncthreads();
  const int nvalid = cnt < 64 ? cnt : 64;
  const bool valid = lane < nvalid;
  const int j = nb[lane];
  float feat[12];
  {
    const float* xr = x + ((size_t)b * N + j) * 9;
#pragma unroll
    for (int k = 0; k < 9; ++k) feat[k] = xr[k];
    const float* pr = pos + ((size_t)b * N + j) * 3;
    feat[9] = pr[0] - cx; feat[10] = pr[1] - cy; feat[11] = pr[2] - cz;
  }
  float acc[64];
  // layer1 (k fully unrolled: only 12)
#pragma unroll
  for (int o = 0; o < 64; ++o) acc[o] = b1[o];
#pragma unroll
  for (int k = 0; k < 12; ++k) {
    float v = feat[k];
#pragma unroll
    for (int o = 0; o < 64; ++o) acc[o] = fmaf(v, w1[k * 64 + o], acc[o]);
  }
#pragma unroll
  for (int o = 0; o < 64; ++o) hbuf[o][lane] = fmaxf(acc[o], 0.f);
  // layer2
#pragma unroll
  for (int o = 0; o < 64; ++o) acc[o] = b2[o];
  {
    float v = hbuf[0][lane];
#pragma unroll 1
    for (int k = 0; k < 64; ++k) {
      float vn = (k < 63) ? hbuf[k + 1][lane] : 0.f;
#pragma unroll
      for (int o = 0; o < 64; ++o) acc[o] = fmaf(v, w2[k * 64 + o], acc[o]);
      v = vn;
    }
  }
#pragma unroll
  for (int o = 0; o < 64; ++o) hbuf[o][lane] = fmaxf(acc[o], 0.f);
  // layer3 + maxpool over edges
  float res0 = 0.f, res1 = 0.f;
#pragma unroll 1
  for (int oc = 0; oc < 4; ++oc) {
    float a3[32];
#pragma unroll
    for (int oo = 0; oo < 32; ++oo) a3[oo] = b3[oc * 32 + oo];
    float v = hbuf[0][lane];
#pragma unroll 1
    for (int k = 0; k < 64; ++k) {
      float vn = (k < 63) ? hbuf[k + 1][lane] : 0.f;
#pragma unroll
      for (int oo = 0; oo < 32; ++oo)
        a3[oo] = fmaf(v, w3[k * 128 + oc * 32 + oo], a3[oo]);
      v = vn;
    }
#pragma unroll
    for (int oo = 0; oo < 32; ++oo) {
      float a = fmaxf(a3[oo], 0.f);
      if (!valid) a = -DEVINF;
#pragma unroll
      for (int off = 1; off < 64; off <<= 1) a = fmaxf(a, __shfl_xor(a, off, 64));
      int o = oc * 32 + oo;
      if (lane == (o & 63)) { if (o < 64) res0 = a; else res1 = a; }
    }
  }
  out[(size_t)bs * 128 + lane] = res0;
  out[(size_t)bs * 128 + 64 + lane] = res1;
}

// ---------------------------------------------------------------------------
// SA2: ball query over 1024 pts (r=0.4) + MLP 131->128->128->256 + maxpool
// ---------------------------------------------------------------------------
__global__ __launch_bounds__(64, 1) void sa2_kernel(
    const float* __restrict__ x1,   // [16][1024][128]
    const float* __restrict__ pos1, // [16][1024][3]
    const float* __restrict__ ctr,  // [16][256][3]
    const float* __restrict__ w1, const float* __restrict__ b1,
    const float* __restrict__ w2, const float* __restrict__ b2,
    const float* __restrict__ w3, const float* __restrict__ b3,
    float* __restrict__ out)        // [16][256][256]
{
  const int N = 1024;
  const float r2 = (float)(0.4 * 0.4);
  const int bs = blockIdx.x;
  const int b = bs >> 8;
  const int lane = threadIdx.x;
  const float cx = ctr[bs * 3 + 0], cy = ctr[bs * 3 + 1], cz = ctr[bs * 3 + 2];
  __shared__ int nb[64];
  __shared__ float hbuf[128][64];
  nb[lane] = 0;
  __syncthreads();
  int cnt = 0;
  {
#pragma clang fp contract(off)
    for (int base = 0; base < N && cnt < 64; base += 64) {
      int i = base + lane;
      const float* p = pos1 + ((size_t)b * N + i) * 3;
      float dx = p[0] - cx, dy = p[1] - cy, dz = p[2] - cz;
      float t0 = dx * dx, t1 = dy * dy, t2 = dz * dz;
      float d2 = (t0 + t1) + t2;
      bool inr = d2 <= r2;
      unsigned long long m = __ballot(inr);
      int posn = cnt + (int)__popcll(m & ((1ull << lane) - 1ull));
      if (inr && posn < 64) nb[posn] = i;
      cnt += (int)__popcll(m);
    }
  }
  __syncthreads();
  const int nvalid = cnt < 64 ? cnt : 64;
  const bool valid = lane < nvalid;
  const int j = nb[lane];
  const float* xr = x1 + ((size_t)b * N + j) * 128;
  const float* pr = pos1 + ((size_t)b * N + j) * 3;
  const float rel0 = pr[0] - cx, rel1 = pr[1] - cy, rel2 = pr[2] - cz;
  float acc[128];
  // layer1: stream x1 row (per-lane gather, prefetch 1 ahead)
#pragma unroll
  for (int o = 0; o < 128; ++o) acc[o] = b1[o];
  {
    float v = xr[0];
#pragma unroll 1
    for (int k = 0; k < 128; ++k) {
      float vn = (k < 127) ? xr[k + 1] : rel0;
#pragma unroll
      for (int o = 0; o < 128; ++o) acc[o] = fmaf(v, w1[k * 128 + o], acc[o]);
      v = vn;
    }
    float rr[3] = {rel0, rel1, rel2};
#pragma unroll
    for (int kk = 0; kk < 3; ++kk) {
      float v2 = rr[kk];
#pragma unroll
      for (int o = 0; o < 128; ++o)
        acc[o] = fmaf(v2, w1[(128 + kk) * 128 + o], acc[o]);
    }
  }
#pragma unroll
  for (int o = 0; o < 128; ++o) hbuf[o][lane] = fmaxf(acc[o], 0.f);
  // layer2
#pragma unroll
  for (int o = 0; o < 128; ++o) acc[o] = b2[o];
  {
    float v = hbuf[0][lane];
#pragma unroll 1
    for (int k = 0; k < 128; ++k) {
      float vn = (k < 127) ? hbuf[k + 1][lane] : 0.f;
#pragma unroll
      for (int o = 0; o < 128; ++o) acc[o] = fmaf(v, w2[k * 128 + o], acc[o]);
      v = vn;
    }
  }
#pragma unroll
  for (int o = 0; o < 128; ++o) hbuf[o][lane] = fmaxf(acc[o], 0.f);
  // layer3 + maxpool: 256 outs in 8 chunks of 32
  float res[4] = {0.f, 0.f, 0.f, 0.f};
#pragma unroll 1
  for (int oc = 0; oc < 8; ++oc) {
    float a3[32];
#pragma unroll
    for (int oo = 0; oo < 32; ++oo) a3[oo] = b3[oc * 32 + oo];
    float v = hbuf[0][lane];
#pragma unroll 1
    for (int k = 0; k < 128; ++k) {
      float vn = (k < 127) ? hbuf[k + 1][lane] : 0.f;
#pragma unroll
      for (int oo = 0; oo < 32; ++oo)
        a3[oo] = fmaf(v, w3[k * 256 + oc * 32 + oo], a3[oo]);
      v = vn;
    }
#pragma unroll
    for (int oo = 0; oo < 32; ++oo) {
      float a = fmaxf(a3[oo], 0.f);
      if (!valid) a = -DEVINF;
#pragma unroll
      for (int off = 1; off < 64; off <<= 1) a = fmaxf(a, __shfl_xor(a, off, 64));
      int o = oc * 32 + oo;
      if (lane == (o & 63)) res[o >> 6] = a;
    }
  }
#pragma unroll
  for (int t = 0; t < 4; ++t) out[(size_t)bs * 256 + t * 64 + lane] = res[t];
}

// ---------------------------------------------------------------------------
// Global SA: MLP 259->256->512->1024 per point, max over 8 points per block.
// lane = output channel; inputs transposed in LDS, read via float4 broadcast.
// ---------------------------------------------------------------------------
__global__ __launch_bounds__(256, 2) void gsa_kernel(
    const float* __restrict__ x2,  // [16][256][256]
    const float* __restrict__ p2,  // [16][256][3]
    const float* __restrict__ w1, const float* __restrict__ b1,
    const float* __restrict__ w2, const float* __restrict__ b2,
    const float* __restrict__ w3, const float* __restrict__ b3,
    float* __restrict__ part)      // [16][32][1024]
{
  const int P = 8;
  const int blk = blockIdx.x;      // 512 blocks
  const int b = blk >> 5, gg = blk & 31;
  const int tid = threadIdx.x;
  __shared__ __align__(16) float in_t[259][P];
  __shared__ __align__(16) float h1_t[256][P];
  __shared__ __align__(16) float h2_t[512][P];
  const int base_pt = gg * P;
#pragma unroll
  for (int p = 0; p < P; ++p)
    in_t[tid][p] = x2[((size_t)(b * 256 + base_pt + p)) * 256 + tid];
  if (tid < 3 * P) {
    int p = tid & (P - 1), c = tid >> 3;
    in_t[256 + c][p] = p2[(b * 256 + base_pt + p) * 3 + c];
  }
  __syncthreads();
  { // layer1
    float acc[P];
#pragma unroll
    for (int p = 0; p < P; ++p) acc[p] = b1[tid];
#pragma unroll 1
    for (int k = 0; k < 259; ++k) {
      float w = w1[k * 256 + tid];
      const float4* vp = (const float4*)in_t[k];
      float4 v0 = vp[0], v1 = vp[1];
      acc[0] = fmaf(v0.x, w, acc[0]); acc[1] = fmaf(v0.y, w, acc[1]);
      acc[2] = fmaf(v0.z, w, acc[2]); acc[3] = fmaf(v0.w, w, acc[3]);
      acc[4] = fmaf(v1.x, w, acc[4]); acc[5] = fmaf(v1.y, w, acc[5]);
      acc[6] = fmaf(v1.z, w, acc[6]); acc[7] = fmaf(v1.w, w, acc[7]);
    }
#pragma unroll
    for (int p = 0; p < P; ++p) h1_t[tid][p] = fmaxf(acc[p], 0.f);
  }
  __syncthreads();
  { // layer2
    float a0[P], a1[P];
#pragma unroll
    for (int p = 0; p < P; ++p) { a0[p] = b2[tid]; a1[p] = b2[tid + 256]; }
#pragma unroll 1
    for (int k = 0; k < 256; ++k) {
      float wa = w2[k * 512 + tid], wb = w2[k * 512 + tid + 256];
      const float4* vp = (const float4*)h1_t[k];
      float4 v0 = vp[0], v1 = vp[1];
      float v[8] = {v0.x, v0.y, v0.z, v0.w, v1.x, v1.y, v1.z, v1.w};
#pragma unroll
      for (int p = 0; p < P; ++p) { a0[p] = fmaf(v[p], wa, a0[p]); a1[p] = fmaf(v[p], wb, a1[p]); }
    }
#pragma unroll
    for (int p = 0; p < P; ++p) {
      h2_t[tid][p] = fmaxf(a0[p], 0.f);
      h2_t[tid + 256][p] = fmaxf(a1[p], 0.f);
    }
  }
  __syncthreads();
  { // layer3 + max over P points
    float a[4][P];
#pragma unroll
    for (int q = 0; q < 4; ++q)
#pragma unroll
      for (int p = 0; p < P; ++p) a[q][p] = b3[q * 256 + tid];
#pragma unroll 1
    for (int k = 0; k < 512; ++k) {
      float w0 = w3[(size_t)k * 1024 + tid];
      float wq1 = w3[(size_t)k * 1024 + tid + 256];
      float wq2 = w3[(size_t)k * 1024 + tid + 512];
      float wq3 = w3[(size_t)k * 1024 + tid + 768];
      const float4* vp = (const float4*)h2_t[k];
      float4 v0 = vp[0], v1 = vp[1];
      float v[8] = {v0.x, v0.y, v0.z, v0.w, v1.x, v1.y, v1.z, v1.w};
#pragma unroll
      for (int p = 0; p < P; ++p) {
        a[0][p] = fmaf(v[p], w0, a[0][p]);
        a[1][p] = fmaf(v[p], wq1, a[1][p]);
        a[2][p] = fmaf(v[p], wq2, a[2][p]);
        a[3][p] = fmaf(v[p], wq3, a[3][p]);
      }
    }
#pragma unroll
    for (int q = 0; q < 4; ++q) {
      float m = -DEVINF;
#pragma unroll
      for (int p = 0; p < P; ++p) m = fmaxf(m, fmaxf(a[q][p], 0.f));
      part[((size_t)(b * 32 + gg)) * 1024 + q * 256 + tid] = m;
    }
  }
}

__global__ __launch_bounds__(256) void gmax_kernel(const float* __restrict__ part,
                                                   float* __restrict__ g) {
  int i = blockIdx.x * 256 + threadIdx.x;  // 16384
  int b = i >> 10, c = i & 1023;
  float m = -DEVINF;
#pragma unroll
  for (int t = 0; t < 32; ++t) m = fmaxf(m, part[((size_t)(b * 32 + t) << 10) + c]);
  g[i] = m;
}

// ---------------------------------------------------------------------------
// Dense layer: out[M][N] = (relu?)(in @ w + b). block=64 (one m, 64 n's).
// in-row reads are wave-uniform -> scalar loads; w reads coalesced.
// ---------------------------------------------------------------------------
__global__ __launch_bounds__(64, 4) void dense_kernel(
    const float* __restrict__ in, const float* __restrict__ w,
    const float* __restrict__ bias, float* __restrict__ out,
    int M, int K, int N, int relu) {
  int nb = N >> 6;
  int m = blockIdx.x / nb, cb = blockIdx.x % nb;
  int n = cb * 64 + threadIdx.x;
  const float* ir = in + (size_t)m * K;
  float acc = bias[n];
  for (int k = 0; k < K; ++k) acc = fmaf(ir[k], w[(size_t)k * N + n], acc);
  if (relu) acc = fmaxf(acc, 0.f);
  out[(size_t)m * N + n] = acc;
}

// ---------------------------------------------------------------------------
extern "C" void kernel_launch(void* const* d_in, const int* in_sizes, int n_in,
                              void* d_out, int out_size, void* d_ws, size_t ws_size,
                              hipStream_t stream) {
  (void)in_sizes; (void)n_in; (void)out_size; (void)ws_size;
  const float* x    = (const float*)d_in[0];
  const float* pos  = (const float*)d_in[1];
  const float* s1w1 = (const float*)d_in[2];  const float* s1b1 = (const float*)d_in[3];
  const float* s1w2 = (const float*)d_in[4];  const float* s1b2 = (const float*)d_in[5];
  const float* s1w3 = (const float*)d_in[6];  const float* s1b3 = (const float*)d_in[7];
  const float* s2w1 = (const float*)d_in[8];  const float* s2b1 = (const float*)d_in[9];
  const float* s2w2 = (const float*)d_in[10]; const float* s2b2 = (const float*)d_in[11];
  const float* s2w3 = (const float*)d_in[12]; const float* s2b3 = (const float*)d_in[13];
  const float* s3w1 = (const float*)d_in[14]; const float* s3b1 = (const float*)d_in[15];
  const float* s3w2 = (const float*)d_in[16]; const float* s3b2 = (const float*)d_in[17];
  const float* s3w3 = (const float*)d_in[18]; const float* s3b3 = (const float*)d_in[19];
  const float* fw1  = (const float*)d_in[20]; const float* fb1  = (const float*)d_in[21];
  const float* fw2  = (const float*)d_in[22]; const float* fb2  = (const float*)d_in[23];
  const float* fw3  = (const float*)d_in[24]; const float* fb3  = (const float*)d_in[25];
  const float* l1w  = (const float*)d_in[26]; const float* l1b  = (const float*)d_in[27];
  const float* l2w  = (const float*)d_in[28]; const float* l2b  = (const float*)d_in[29];
  const float* l3w  = (const float*)d_in[30]; const float* l3b  = (const float*)d_in[31];
  const float* l4w  = (const float*)d_in[32]; const float* l4b  = (const float*)d_in[33];
  const float* l5w  = (const float*)d_in[34]; const float* l5b  = (const float*)d_in[35];
  float* out = (float*)d_out;

  float* ws = (float*)d_ws;
  float* p1   = ws;                  // 16*1024*3    = 49152
  float* x1   = p1 + 49152;          // 16*1024*128  = 2097152
  float* p2   = x1 + 2097152;        // 16*256*3     = 12288
  float* x2   = p2 + 12288;          // 16*256*256   = 1048576
  float* part = x2 + 1048576;        // 16*32*1024   = 524288
  float* g    = part + 524288;       // 16*1024      = 16384
  float* hA   = g + 16384;           // 16*512
  float* hB   = hA + 8192;           // 16*256
  float* hC   = hB + 4096;           // 16*256
  float* hD   = hC + 4096;           // 4*512
  float* hE   = hD + 2048;           // 4*512
  float* hF   = hE + 2048;           // 4*256
  float* hG   = hF + 1024;           // 4*128

  fps_kernel<2048, 8><<<16, 256, 0, stream>>>(pos, 1024, p1);
  fps_kernel<1024, 4><<<16, 256, 0, stream>>>(p1, 256, p2);
  sa1_kernel<<<16 * 1024, 64, 0, stream>>>(x, pos, p1, s1w1, s1b1, s1w2, s1b2,
                                           s1w3, s1b3, x1);
  sa2_kernel<<<16 * 256, 64, 0, stream>>>(x1, p1, p2, s2w1, s2b1, s2w2, s2b2,
                                          s2w3, s2b3, x2);
  gsa_kernel<<<512, 256, 0, stream>>>(x2, p2, s3w1, s3b1, s3w2, s3b2, s3w3, s3b3, part);
  gmax_kernel<<<64, 256, 0, stream>>>(part, g);
  dense_kernel<<<16 * 8, 64, 0, stream>>>(g,  l1w, l1b, hA, 16, 1024, 512, 1);
  dense_kernel<<<16 * 4, 64, 0, stream>>>(hA, l2w, l2b, hB, 16, 512, 256, 1);
  dense_kernel<<<16 * 4, 64, 0, stream>>>(hB, l3w, l3b, hC, 16, 256, 256, 0);
  // hC [16][256] viewed as [4][1024]
  dense_kernel<<<4 * 8, 64, 0, stream>>>(hC, fw1, fb1, hD, 4, 1024, 512, 1);
  dense_kernel<<<4 * 8, 64, 0, stream>>>(hD, fw2, fb2, hE, 4, 512, 512, 1);
  dense_kernel<<<4 * 4, 64, 0, stream>>>(hE, fw3, fb3, hF, 4, 512, 256, 1);
  dense_kernel<<<4 * 2, 64, 0, stream>>>(hF, l4w, l4b, hG, 4, 256, 128, 1);
  dense_kernel<<<4 * 2, 64, 0, stream>>>(hG, l5w, l5b, out, 4, 128, 128, 0);
}